// Round 12
// baseline (42.151 us; speedup 1.0000x reference)
//
#include <hip/hip_runtime.h>
#include <hip/hip_bf16.h>
#include <math.h>

constexpr int T = 128;
constexpr int B = 128;
constexpr int R = 512;
constexpr int NS = 256;   // 2*T slots

typedef __attribute__((ext_vector_type(8))) short bf16x8;
typedef __attribute__((ext_vector_type(4))) float f32x4;

static __device__ __forceinline__ ushort f2bf(float f) {
    union { float f; unsigned u; } v; v.f = f;
    unsigned r = v.u + 0x7fffu + ((v.u >> 16) & 1u);   // RNE
    return (ushort)(r >> 16);
}

// ---------------------------------------------------------------------------
// Kernel 1: closed-form weights (R7 exact — best measured). Block = one t,
// 512 thr (8 waves). A0: stage e=d1+d2-u into LDS; A1: serial H chain;
// A2: per-wave stripe minima; B: 16-iter p-loop with shfl_xor cross-batch
// max; C: zero-fill tail.
// ---------------------------------------------------------------------------
__global__ __launch_bounds__(512) void weights(
    const float* __restrict__ u, const float* __restrict__ d1,
    const float* __restrict__ d2, ushort* __restrict__ w)
{
    const int t    = blockIdx.x;
    const int tid  = threadIdx.x;
    const int wv   = tid >> 6;          // 0..7
    const int lane = tid & 63;
    __shared__ float eH[T][B];          // 64 KB: e, overwritten with H
    __shared__ float smin[8][B];        // 4 KB stripe minima

    // Phase A0
    const int nfl = t * B;
    for (int i = tid * 4; i < nfl; i += 2048) {
        const float4 a  = *(const float4*)(d1 + i);
        const float4 b4 = *(const float4*)(d2 + i);
        const float4 c4 = *(const float4*)(u + i);
        *(float4*)(&eH[0][0] + i) =
            make_float4(a.x + b4.x - c4.x, a.y + b4.y - c4.y,
                        a.z + b4.z - c4.z, a.w + b4.w - c4.w);
    }
    __syncthreads();

    // Phase A1
    if (tid < B) {
        float h = 0.f;
        #pragma unroll 4
        for (int tt = 0; tt < t; ++tt) {
            h = fmaxf(0.f, h + eH[tt][tid]);
            eH[tt][tid] = h;
        }
    }
    __syncthreads();

    const int b0 = lane, b1 = lane + 64;

    // Phase A2: stripe minima
    {
        const int rs = wv * 16;
        const int re = min(rs + 16, t);     // exclusive
        float sa = 1e30f, sb = 1e30f;
        for (int tau = rs; tau < re; ++tau) {
            sa = fminf(sa, eH[tau][b0]);
            sb = fminf(sb, eH[tau][b1]);
        }
        smin[wv][b0] = sa;
        smin[wv][b1] = sb;
    }
    __syncthreads();

    const float Ht1a = (t > 0) ? eH[t-1][b0] : 0.f;
    const float Ht1b = (t > 0) ? eH[t-1][b1] : 0.f;
    const float Hpa  = Ht1a + d1[t*B+b0] + d2[t*B+b0];   // H'_t
    const float Hpb  = Ht1b + d1[t*B+b1] + d2[t*B+b1];
    const float Aa   = u[t*B+b0] - Hpa;
    const float Ab   = u[t*B+b1] - Hpb;

    ushort* wrow0 = w + ((size_t)t * B + b0) * NS;
    ushort* wrow1 = w + ((size_t)t * B + b1) * NS;

    const int plo = wv * 16;
    if (plo <= t) {
        const int pe = min(plo + 15, t);
        float ma = 1e30f, mb = 1e30f;       // seed: min over stripes > wv
        #pragma unroll
        for (int s = 0; s < 8; ++s) {
            if (s > wv) { ma = fminf(ma, smin[s][b0]); mb = fminf(mb, smin[s][b1]); }
        }
        float s2a = 0.f, s3a = 0.f, s2b = 0.f, s3b = 0.f;
        float nd1a = d1[pe*B+b0], nd1b = d1[pe*B+b1];
        float nd2a = d2[pe*B+b0], nd2b = d2[pe*B+b1];
        for (int p = pe; p >= plo; --p) {
            const float d1a = nd1a, d1b = nd1b, d2a = nd2a, d2b = nd2b;
            if (p > plo) {
                nd1a = d1[(p-1)*B+b0]; nd1b = d1[(p-1)*B+b1];
                nd2a = d2[(p-1)*B+b0]; nd2b = d2[(p-1)*B+b1];
            }
            if (p < t) { ma = fminf(ma, eH[p][b0]); mb = fminf(mb, eH[p][b1]); }
            const float basea = (p > 0) ? eH[p-1][b0] : 0.f;
            const float baseb = (p > 0) ? eH[p-1][b1] : 0.f;
            const float top0a = basea + d1a, top0b = baseb + d1b;
            const float top1a = top0a + d2a, top1b = top0b + d2b;

            const float sa0 = fminf(fmaxf(ma - basea, 0.f), d1a);
            const float sb0 = fminf(fmaxf(mb - baseb, 0.f), d1b);
            const float sa1 = fminf(fmaxf(ma - top0a, 0.f), d2a);
            const float sb1 = fminf(fmaxf(mb - top0b, 0.f), d2b);

            float cand0 = fmaxf(Aa + fminf(top0a, ma), Ab + fminf(top0b, mb));
            float cand1 = fmaxf(Aa + fminf(top1a, ma), Ab + fminf(top1b, mb));
            #pragma unroll
            for (int off = 32; off >= 1; off >>= 1) {
                cand0 = fmaxf(cand0, __shfl_xor(cand0, off));
                cand1 = fmaxf(cand1, __shfl_xor(cand1, off));
            }

            const float w0a = fminf(sa0, cand0), w0b = fminf(sb0, cand0);
            const float w1a = fminf(sa1, cand1), w1b = fminf(sb1, cand1);
            if (p & 1) { s2a = w0a; s3a = w1a; s2b = w0b; s3b = w1b; }
            else {
                const int g = p >> 1;
                *(ushort4*)(wrow0 + 4*g) =
                    make_ushort4(f2bf(w0a), f2bf(w1a), f2bf(s2a), f2bf(s3a));
                *(ushort4*)(wrow1 + 4*g) =
                    make_ushort4(f2bf(w0b), f2bf(w1b), f2bf(s2b), f2bf(s3b));
            }
        }
    }

    // Phase C
    const int gstart = (t >> 1) + 1;
    const int ng = (NS / 4) - gstart;
    if (ng > 0) {
        const ushort4 z = make_ushort4(0, 0, 0, 0);
        const int total = ng * B;
        for (int idx = tid; idx < total; idx += 512) {
            const int gi = idx % ng;
            const int bb = idx / ng;
            *(ushort4*)(w + ((size_t)t*B + bb)*NS + 4*(gstart + gi)) = z;
        }
    }
}

// ---------------------------------------------------------------------------
// Kernel 2: bf16 MFMA GEMM — R11 structure, SINGLE CHANGE: V/A loads issued
// THREE chunks ahead into 3 rotating register sets (2 LDS buffers kept).
// Pipeline: at iter c — VLOAD(set c%3, chunk c+3); barrier; MFMA from
// Bs[c&1] with a[c%3]; BW(Bs[(c+1)&1], set (c+1)%3); ALOAD(set c%3, c+3).
// Load-to-wait distance ~2 full iterations > HBM latency.
// Block = (b, r-tile 128), grid 512; 512 thr = 8 waves; __launch_bounds__
// (512,4) pins VGPR <= 128 for 2 blocks/CU. Zero-skip: chunk c <= wv only.
// ---------------------------------------------------------------------------
#define RT 128
__global__ __launch_bounds__(512, 4) void gemm_mfma(
    const ushort* __restrict__ w, const float* __restrict__ v1,
    const float* __restrict__ v2, float* __restrict__ out)
{
    const int b    = blockIdx.x;
    const int r0   = blockIdx.y * RT;
    const int tid  = threadIdx.x;
    const int wv   = tid >> 6;          // 0..7
    const int lane = tid & 63;

    __shared__ ushort Bs[2][128][40];   // [r][j] bf16, 20 KB

    // B staging: thread = (slot-pair p2 0..15, r-quad rseg 0..31)
    const int p2   = tid & 15;
    const int rseg = tid >> 4;          // 0..31
    const float* v1b = v1 + (size_t)b * R + r0 + rseg * 4;
    const float* v2b = v2 + (size_t)b * R + r0 + rseg * 4;

    // A direct: wave wv, lane row tb = wv*16 + (lane&15), k-off ko
    const int tb = wv * 16 + (lane & 15);
    const int ko = (lane >> 4) * 8;
    const ushort* warow = w + ((size_t)tb * B + b) * NS + ko;

    f32x4 acc[8];
    const f32x4 zz = {0.f, 0.f, 0.f, 0.f};
    #pragma unroll
    for (int i = 0; i < 8; ++i) acc[i] = zz;

    float4 sv1[3], sv2[3];
    bf16x8 a[3];

    #define VLOAD(s, c) do {                                            \
        if ((c) < 8) {                                                  \
            const size_t off_ = (size_t)((c) * 16 + p2) * B * R;        \
            sv1[s] = *(const float4*)(v1b + off_);                      \
            sv2[s] = *(const float4*)(v2b + off_);                      \
        }                                                               \
    } while (0)

    #define ALOAD(s, c) do {                                            \
        if ((c) < 8 && (c) <= wv) {                                     \
            a[s] = *(const bf16x8*)(warow + (c) * 32);                  \
        }                                                               \
    } while (0)

    #define BW(buf, s) do {                                             \
        const float* f1_ = (const float*)&sv1[s];                       \
        const float* f2_ = (const float*)&sv2[s];                       \
        _Pragma("unroll")                                               \
        for (int i_ = 0; i_ < 4; ++i_) {                                \
            unsigned pk_ = (unsigned)f2bf(f1_[i_]) |                    \
                           ((unsigned)f2bf(f2_[i_]) << 16);             \
            *(unsigned*)&Bs[buf][rseg * 4 + i_][p2 * 2] = pk_;          \
        }                                                               \
    } while (0)

    // prologue: fill the 3-deep register pipeline, write chunk 0 to LDS
    VLOAD(0, 0); ALOAD(0, 0);
    VLOAD(1, 1); ALOAD(1, 1);
    VLOAD(2, 2); ALOAD(2, 2);
    BW(0, 0);                 // waits chunk-0 V only (chunks 1,2 stay in flight)

    #pragma unroll
    for (int c = 0; c < 8; ++c) {
        VLOAD(c % 3, c + 3);            // refill set freed at bottom of c-1
        __syncthreads();                // Bs[c&1] (chunk c) now visible
        if (c <= wv) {                  // chunks beyond this are all-zero A
            #pragma unroll
            for (int cf = 0; cf < 8; ++cf) {
                bf16x8 bb = *(const bf16x8*)&Bs[c & 1][cf*16 + (lane & 15)][ko];
                acc[cf] = __builtin_amdgcn_mfma_f32_16x16x32_bf16(a[c % 3], bb, acc[cf], 0, 0, 0);
            }
        }
        if (c < 7) BW((c + 1) & 1, (c + 1) % 3);   // chunk c+1 -> LDS
        ALOAD(c % 3, c + 3);            // a[c%3] free after MFMA above
    }

    // epilogue: D col = lane&15 (r), row = (lane>>4)*4 + i (t)
    const int dcol  = lane & 15;
    const int drow4 = (lane >> 4) * 4;
    #pragma unroll
    for (int cf = 0; cf < 8; ++cf) {
        const int rg = r0 + cf * 16 + dcol;
        #pragma unroll
        for (int i = 0; i < 4; ++i) {
            const int tg = wv * 16 + drow4 + i;
            out[((size_t)tg * B + b) * R + rg] = acc[cf][i];
        }
    }
    #undef VLOAD
    #undef ALOAD
    #undef BW
}

extern "C" void kernel_launch(void* const* d_in, const int* in_sizes, int n_in,
                              void* d_out, int out_size, void* d_ws, size_t ws_size,
                              hipStream_t stream) {
    const float* u  = (const float*)d_in[0];
    const float* d1 = (const float*)d_in[1];
    const float* d2 = (const float*)d_in[2];
    const float* v1 = (const float*)d_in[3];
    const float* v2 = (const float*)d_in[4];
    float* out = (float*)d_out;
    ushort* w  = (ushort*)d_ws;          // 8.39 MB bf16

    weights<<<dim3(T), dim3(512), 0, stream>>>(u, d1, d2, w);
    // grid.x = b (fastest): all r-tiles of a given b land on XCD b%8 -> w L2 reuse
    gemm_mfma<<<dim3(B, R / RT), dim3(512), 0, stream>>>(w, v1, v2, out);
}

// Round 13
// 40.747 us; speedup vs baseline: 1.0345x; 1.0345x over previous
//
#include <hip/hip_runtime.h>
#include <hip/hip_bf16.h>
#include <math.h>

constexpr int T = 128;
constexpr int B = 128;
constexpr int R = 512;
constexpr int NS = 256;   // 2*T slots

typedef __attribute__((ext_vector_type(8))) short bf16x8;
typedef __attribute__((ext_vector_type(4))) float f32x4;

static __device__ __forceinline__ ushort f2bf(float f) {
    union { float f; unsigned u; } v; v.f = f;
    unsigned r = v.u + 0x7fffu + ((v.u >> 16) & 1u);   // RNE
    return (ushort)(r >> 16);
}

// ---------------------------------------------------------------------------
// Kernel 1: closed-form weights (R7 exact — best measured). Block = one t,
// 512 thr (8 waves). A0: stage e=d1+d2-u into LDS; A1: serial H chain;
// A2: per-wave stripe minima; B: 16-iter p-loop with shfl_xor cross-batch
// max; C: zero-fill tail.
// ---------------------------------------------------------------------------
__global__ __launch_bounds__(512) void weights(
    const float* __restrict__ u, const float* __restrict__ d1,
    const float* __restrict__ d2, ushort* __restrict__ w)
{
    const int t    = blockIdx.x;
    const int tid  = threadIdx.x;
    const int wv   = tid >> 6;          // 0..7
    const int lane = tid & 63;
    __shared__ float eH[T][B];          // 64 KB: e, overwritten with H
    __shared__ float smin[8][B];        // 4 KB stripe minima

    // Phase A0
    const int nfl = t * B;
    for (int i = tid * 4; i < nfl; i += 2048) {
        const float4 a  = *(const float4*)(d1 + i);
        const float4 b4 = *(const float4*)(d2 + i);
        const float4 c4 = *(const float4*)(u + i);
        *(float4*)(&eH[0][0] + i) =
            make_float4(a.x + b4.x - c4.x, a.y + b4.y - c4.y,
                        a.z + b4.z - c4.z, a.w + b4.w - c4.w);
    }
    __syncthreads();

    // Phase A1
    if (tid < B) {
        float h = 0.f;
        #pragma unroll 4
        for (int tt = 0; tt < t; ++tt) {
            h = fmaxf(0.f, h + eH[tt][tid]);
            eH[tt][tid] = h;
        }
    }
    __syncthreads();

    const int b0 = lane, b1 = lane + 64;

    // Phase A2: stripe minima
    {
        const int rs = wv * 16;
        const int re = min(rs + 16, t);     // exclusive
        float sa = 1e30f, sb = 1e30f;
        for (int tau = rs; tau < re; ++tau) {
            sa = fminf(sa, eH[tau][b0]);
            sb = fminf(sb, eH[tau][b1]);
        }
        smin[wv][b0] = sa;
        smin[wv][b1] = sb;
    }
    __syncthreads();

    const float Ht1a = (t > 0) ? eH[t-1][b0] : 0.f;
    const float Ht1b = (t > 0) ? eH[t-1][b1] : 0.f;
    const float Hpa  = Ht1a + d1[t*B+b0] + d2[t*B+b0];   // H'_t
    const float Hpb  = Ht1b + d1[t*B+b1] + d2[t*B+b1];
    const float Aa   = u[t*B+b0] - Hpa;
    const float Ab   = u[t*B+b1] - Hpb;

    ushort* wrow0 = w + ((size_t)t * B + b0) * NS;
    ushort* wrow1 = w + ((size_t)t * B + b1) * NS;

    const int plo = wv * 16;
    if (plo <= t) {
        const int pe = min(plo + 15, t);
        float ma = 1e30f, mb = 1e30f;       // seed: min over stripes > wv
        #pragma unroll
        for (int s = 0; s < 8; ++s) {
            if (s > wv) { ma = fminf(ma, smin[s][b0]); mb = fminf(mb, smin[s][b1]); }
        }
        float s2a = 0.f, s3a = 0.f, s2b = 0.f, s3b = 0.f;
        float nd1a = d1[pe*B+b0], nd1b = d1[pe*B+b1];
        float nd2a = d2[pe*B+b0], nd2b = d2[pe*B+b1];
        for (int p = pe; p >= plo; --p) {
            const float d1a = nd1a, d1b = nd1b, d2a = nd2a, d2b = nd2b;
            if (p > plo) {
                nd1a = d1[(p-1)*B+b0]; nd1b = d1[(p-1)*B+b1];
                nd2a = d2[(p-1)*B+b0]; nd2b = d2[(p-1)*B+b1];
            }
            if (p < t) { ma = fminf(ma, eH[p][b0]); mb = fminf(mb, eH[p][b1]); }
            const float basea = (p > 0) ? eH[p-1][b0] : 0.f;
            const float baseb = (p > 0) ? eH[p-1][b1] : 0.f;
            const float top0a = basea + d1a, top0b = baseb + d1b;
            const float top1a = top0a + d2a, top1b = top0b + d2b;

            const float sa0 = fminf(fmaxf(ma - basea, 0.f), d1a);
            const float sb0 = fminf(fmaxf(mb - baseb, 0.f), d1b);
            const float sa1 = fminf(fmaxf(ma - top0a, 0.f), d2a);
            const float sb1 = fminf(fmaxf(mb - top0b, 0.f), d2b);

            float cand0 = fmaxf(Aa + fminf(top0a, ma), Ab + fminf(top0b, mb));
            float cand1 = fmaxf(Aa + fminf(top1a, ma), Ab + fminf(top1b, mb));
            #pragma unroll
            for (int off = 32; off >= 1; off >>= 1) {
                cand0 = fmaxf(cand0, __shfl_xor(cand0, off));
                cand1 = fmaxf(cand1, __shfl_xor(cand1, off));
            }

            const float w0a = fminf(sa0, cand0), w0b = fminf(sb0, cand0);
            const float w1a = fminf(sa1, cand1), w1b = fminf(sb1, cand1);
            if (p & 1) { s2a = w0a; s3a = w1a; s2b = w0b; s3b = w1b; }
            else {
                const int g = p >> 1;
                *(ushort4*)(wrow0 + 4*g) =
                    make_ushort4(f2bf(w0a), f2bf(w1a), f2bf(s2a), f2bf(s3a));
                *(ushort4*)(wrow1 + 4*g) =
                    make_ushort4(f2bf(w0b), f2bf(w1b), f2bf(s2b), f2bf(s3b));
            }
        }
    }

    // Phase C
    const int gstart = (t >> 1) + 1;
    const int ng = (NS / 4) - gstart;
    if (ng > 0) {
        const ushort4 z = make_ushort4(0, 0, 0, 0);
        const int total = ng * B;
        for (int idx = tid; idx < total; idx += 512) {
            const int gi = idx % ng;
            const int bb = idx / ng;
            *(ushort4*)(w + ((size_t)t*B + bb)*NS + 4*(gstart + gi)) = z;
        }
    }
}

// ---------------------------------------------------------------------------
// Kernel 2: bf16 MFMA GEMM — R11 structure, SINGLE CHANGE: raw s_barrier
// (no vmcnt drain) + manual lgkmcnt(0), T14 write-late schedule:
//   iter c: [lgkm0; barrier A] BW(chunk c+1)  VLOAD/ALOAD(chunk c+2)
//           [lgkm0; barrier B] MFMA(c)
// Global loads issued at iter c are waited (register dep) at BW in iter c+1 —
// a full iteration in flight, surviving the barriers (raw s_barrier has no
// vmcnt(0) drain, unlike __syncthreads). Barrier A protects write-after-read
// of Bs; barrier B publishes BW. sched_barrier(0) pins against hoisting.
// Block = (b, r-tile 128), grid 512; 512 thr = 8 waves; zero-skip c <= wv.
// ---------------------------------------------------------------------------
#define RT 128
__global__ __launch_bounds__(512) void gemm_mfma(
    const ushort* __restrict__ w, const float* __restrict__ v1,
    const float* __restrict__ v2, float* __restrict__ out)
{
    const int b    = blockIdx.x;
    const int r0   = blockIdx.y * RT;
    const int tid  = threadIdx.x;
    const int wv   = tid >> 6;          // 0..7
    const int lane = tid & 63;

    __shared__ ushort Bs[2][128][40];   // [r][j] bf16, 20 KB

    // B staging: thread = (slot-pair p2 0..15, r-quad rseg 0..31)
    const int p2   = tid & 15;
    const int rseg = tid >> 4;          // 0..31
    const float* v1b = v1 + (size_t)b * R + r0 + rseg * 4;
    const float* v2b = v2 + (size_t)b * R + r0 + rseg * 4;

    // A direct: wave wv, lane row tb = wv*16 + (lane&15), k-off ko
    const int tb = wv * 16 + (lane & 15);
    const int ko = (lane >> 4) * 8;
    const ushort* warow = w + ((size_t)tb * B + b) * NS + ko;

    f32x4 acc[8];
    const f32x4 zz = {0.f, 0.f, 0.f, 0.f};
    #pragma unroll
    for (int i = 0; i < 8; ++i) acc[i] = zz;

    float4 sv1[2], sv2[2];
    bf16x8 a[3];

    #define VLOAD(s, c) do {                                            \
        if ((c) < 8) {                                                  \
            const size_t off_ = (size_t)((c) * 16 + p2) * B * R;        \
            sv1[s] = *(const float4*)(v1b + off_);                      \
            sv2[s] = *(const float4*)(v2b + off_);                      \
        }                                                               \
    } while (0)

    #define ALOAD(s, c) do {                                            \
        if ((c) < 8 && (c) <= wv) {                                     \
            a[s] = *(const bf16x8*)(warow + (c) * 32);                  \
        }                                                               \
    } while (0)

    #define BW(buf, s) do {                                             \
        const float* f1_ = (const float*)&sv1[s];                       \
        const float* f2_ = (const float*)&sv2[s];                       \
        _Pragma("unroll")                                               \
        for (int i_ = 0; i_ < 4; ++i_) {                                \
            unsigned pk_ = (unsigned)f2bf(f1_[i_]) |                    \
                           ((unsigned)f2bf(f2_[i_]) << 16);             \
            *(unsigned*)&Bs[buf][rseg * 4 + i_][p2 * 2] = pk_;          \
        }                                                               \
    } while (0)

    // prologue: chunk 0 -> Bs[0]; chunk 1 loads in flight
    VLOAD(0, 0); ALOAD(0, 0);
    BW(0, 0);                 // waits chunk-0 loads via register dep
    VLOAD(1, 1); ALOAD(1, 1); // chunk 1 in flight across barriers below

    #pragma unroll
    for (int c = 0; c < 8; ++c) {
        // barrier A: all waves' ds_reads of Bs (prev MFMA) are consumed
        asm volatile("s_waitcnt lgkmcnt(0)" ::: "memory");
        __builtin_amdgcn_s_barrier();
        __builtin_amdgcn_sched_barrier(0);

        if (c < 7) BW((c + 1) & 1, (c + 1) & 1);   // chunk c+1 -> LDS
        VLOAD(c & 1, c + 2);                       // chunk c+2 in flight
        ALOAD((c + 2) % 3, c + 2);

        // barrier B: publish BW(c+1); chunk c (published iter c-1) readable
        asm volatile("s_waitcnt lgkmcnt(0)" ::: "memory");
        __builtin_amdgcn_s_barrier();
        __builtin_amdgcn_sched_barrier(0);

        if (c <= wv) {                  // chunks beyond this are all-zero A
            #pragma unroll
            for (int cf = 0; cf < 8; ++cf) {
                bf16x8 bb = *(const bf16x8*)&Bs[c & 1][cf*16 + (lane & 15)][ko];
                acc[cf] = __builtin_amdgcn_mfma_f32_16x16x32_bf16(a[c % 3], bb, acc[cf], 0, 0, 0);
            }
        }
    }

    // epilogue: D col = lane&15 (r), row = (lane>>4)*4 + i (t)
    const int dcol  = lane & 15;
    const int drow4 = (lane >> 4) * 4;
    #pragma unroll
    for (int cf = 0; cf < 8; ++cf) {
        const int rg = r0 + cf * 16 + dcol;
        #pragma unroll
        for (int i = 0; i < 4; ++i) {
            const int tg = wv * 16 + drow4 + i;
            out[((size_t)tg * B + b) * R + rg] = acc[cf][i];
        }
    }
    #undef VLOAD
    #undef ALOAD
    #undef BW
}

extern "C" void kernel_launch(void* const* d_in, const int* in_sizes, int n_in,
                              void* d_out, int out_size, void* d_ws, size_t ws_size,
                              hipStream_t stream) {
    const float* u  = (const float*)d_in[0];
    const float* d1 = (const float*)d_in[1];
    const float* d2 = (const float*)d_in[2];
    const float* v1 = (const float*)d_in[3];
    const float* v2 = (const float*)d_in[4];
    float* out = (float*)d_out;
    ushort* w  = (ushort*)d_ws;          // 8.39 MB bf16

    weights<<<dim3(T), dim3(512), 0, stream>>>(u, d1, d2, w);
    // grid.x = b (fastest): all r-tiles of a given b land on XCD b%8 -> w L2 reuse
    gemm_mfma<<<dim3(B, R / RT), dim3(512), 0, stream>>>(w, v1, v2, out);
}